// Round 12
// baseline (116.629 us; speedup 1.0000x reference)
//
#include <hip/hip_runtime.h>
#include <hip/hip_bf16.h>

typedef __attribute__((ext_vector_type(8))) short short8;
typedef __attribute__((ext_vector_type(4))) float f32x4;
typedef __attribute__((ext_vector_type(16))) float f32x16;
typedef unsigned short u16;
typedef unsigned int u32;

static __device__ __forceinline__ u16 f2b(float f) {
  __hip_bfloat16 h = __float2bfloat16(f);
  return __builtin_bit_cast(u16, h);
}
static __device__ __forceinline__ float b2f(u16 v) {
  return __builtin_bit_cast(float, ((u32)v) << 16);
}
static __device__ __forceinline__ u32 pk2(float lo, float hi) {
  return (u32)f2b(lo) | ((u32)f2b(hi) << 16);
}
static __device__ __forceinline__ u32 cvtpk(float lo, float hi) {
  u32 r;
  asm("v_cvt_pk_bf16_f32 %0, %1, %2" : "=v"(r) : "v"(lo), "v"(hi));
  return r;
}
static __device__ __forceinline__ void atomPk(u16* p, u32 d) {
  asm volatile("global_atomic_pk_add_bf16 %0, %1, off" ::"v"(p), "v"(d) : "memory");
}

static __device__ __forceinline__ void gload16(const void* g, void* l) {
  __builtin_amdgcn_global_load_lds((const __attribute__((address_space(1))) void*)g,
                                   (__attribute__((address_space(3))) void*)l, 16, 0, 0);
}

// Raw s_barrier has no compiler memory fence; add zero-cost scheduler+IR fences.
static __device__ __forceinline__ void barrier_fenced() {
  __builtin_amdgcn_sched_barrier(0);
  asm volatile("" ::: "memory");
  __builtin_amdgcn_s_barrier();
  __builtin_amdgcn_sched_barrier(0);
  asm volatile("" ::: "memory");
}

// ---------------- merged prep: x->bf16 | W_attn K-slice transpose | W_proj transpose ------
__global__ __launch_bounds__(256) void prep(const float4* __restrict__ x4,
                                            uint2* __restrict__ xb,
                                            const float* __restrict__ W_attn,
                                            u16* __restrict__ Wkt,
                                            const float* __restrict__ W_proj,
                                            u16* __restrict__ Wpt) {
  __shared__ u16 tile[32][33];
  int bid = blockIdx.x, t = threadIdx.x;
  if (bid < 4096) {
    int i = bid * 256 + t;
    float4 v = x4[i];
    uint2 o;
    o.x = pk2(v.x, v.y);
    o.y = pk2(v.z, v.w);
    xb[i] = o;
    return;
  }
  const float* in;
  u16* out;
  int in_rs, col_off, blk;
  if (bid < 5120) {
    in = W_attn; out = Wkt; in_rs = 3072; col_off = 1024; blk = bid - 4096;
  } else {
    in = W_proj; out = Wpt; in_rs = 1024; col_off = 0; blk = bid - 5120;
  }
  int tx = t & 31, ty = t >> 5;
  int r0 = (blk >> 5) * 32, c0 = (blk & 31) * 32;
#pragma unroll
  for (int i = 0; i < 4; ++i) {
    int r = r0 + ty + i * 8;
    tile[ty + i * 8][tx] = f2b(in[(size_t)r * in_rs + col_off + c0 + tx]);
  }
  __syncthreads();
#pragma unroll
  for (int i = 0; i < 4; ++i) {
    int c = c0 + ty + i * 8;
    out[(size_t)c * 1024 + r0 + tx] = tile[tx][ty + i * 8];
  }
}

// ---------------- GEMM: C[M][N] = A[M][K] * Bt[N][K]^T + bias ----------------
// MODE 0: bf16 C + fused per-head transpose. MODE 1: f32 C.
template <int MODE>
__global__ __launch_bounds__(256) void gemm_bias(const u16* __restrict__ A,
                                                 const u16* __restrict__ Bt,
                                                 const float* __restrict__ bias,
                                                 void* __restrict__ Cp, u16* __restrict__ Ktp,
                                                 int M, int N, int K) {
  __shared__ char lds[3][24576];
  int tid = threadIdx.x, lane = tid & 63, wid = tid >> 6;
  int lr = lane & 15, lh = lane >> 4;
  int p = blockIdx.x;
  int m0 = (p >> 3) << 6, n0 = (p & 7) << 7;
  int wm = wid >> 1, wn = wid & 1;
  f32x4 acc[2][4] = {};
  int srow = lane >> 3;
  int scol = ((lane & 7) << 4) ^ (srow << 4);
  const char* Ab = (const char*)A;
  const char* Bb = (const char*)Bt;
  int r0 = wid * 8;
  const int NT = K >> 6;

  auto stage = [&](char* buf, int k0) {
    char* lA = buf;
    char* lB = buf + 8192;
    gload16(Ab + ((size_t)(m0 + r0 + srow) * K + k0) * 2 + scol, lA + r0 * 128);
    gload16(Ab + ((size_t)(m0 + 32 + r0 + srow) * K + k0) * 2 + scol, lA + (32 + r0) * 128);
#pragma unroll
    for (int i = 0; i < 4; ++i)
      gload16(Bb + ((size_t)(n0 + i * 32 + r0 + srow) * K + k0) * 2 + scol,
              lB + (i * 32 + r0) * 128);
  };

  stage(lds[0], 0);
  stage(lds[1], 64);
  for (int t = 0; t < NT; ++t) {
    if (t + 1 < NT)
      asm volatile("s_waitcnt vmcnt(6) lgkmcnt(0)" ::: "memory");
    else
      asm volatile("s_waitcnt vmcnt(0) lgkmcnt(0)" ::: "memory");
    barrier_fenced();
    char* lA = lds[t % 3];
    char* lB = lA + 8192;
    short8 af[2][2], bfr[4][2];
#pragma unroll
    for (int mi = 0; mi < 2; ++mi)
#pragma unroll
      for (int ks = 0; ks < 2; ++ks) {
        int row = wm * 32 + mi * 16 + lr;
        af[mi][ks] = *(const short8*)(lA + row * 128 + ((ks * 64 + lh * 16) ^ ((row & 7) << 4)));
      }
#pragma unroll
    for (int ni = 0; ni < 4; ++ni)
#pragma unroll
      for (int ks = 0; ks < 2; ++ks) {
        int row = wn * 64 + ni * 16 + lr;
        bfr[ni][ks] = *(const short8*)(lB + row * 128 + ((ks * 64 + lh * 16) ^ ((row & 7) << 4)));
      }
    __builtin_amdgcn_s_setprio(1);
#pragma unroll
    for (int ks = 0; ks < 2; ++ks)
#pragma unroll
      for (int mi = 0; mi < 2; ++mi)
#pragma unroll
        for (int ni = 0; ni < 4; ++ni)
          acc[mi][ni] = __builtin_amdgcn_mfma_f32_16x16x32_bf16(af[mi][ks], bfr[ni][ks],
                                                                acc[mi][ni], 0, 0, 0);
    __builtin_amdgcn_s_setprio(0);
    if (t + 2 < NT) stage(lds[(t + 2) % 3], (t + 2) << 6);
  }
#pragma unroll
  for (int mi = 0; mi < 2; ++mi)
#pragma unroll
    for (int ni = 0; ni < 4; ++ni) {
      int col = n0 + wn * 64 + ni * 16 + lr;
      float bz = bias[col];
      int row0 = m0 + wm * 32 + mi * 16 + lh * 4;
      if (MODE == 1) {
#pragma unroll
        for (int r = 0; r < 4; ++r)
          ((float*)Cp)[(size_t)(row0 + r) * N + col] = acc[mi][ni][r] + bz;
      } else {
        ushort4 q;
        u16* qa = (u16*)&q;
#pragma unroll
        for (int r = 0; r < 4; ++r) {
          u16 v = f2b(acc[mi][ni][r] + bz);
          qa[r] = v;
          ((u16*)Cp)[(size_t)(row0 + r) * N + col] = v;
        }
        *(ushort4*)(Ktp + ((size_t)((row0 >> 11) * 1024 + col)) * 2048 + (row0 & 2047)) = q;
      }
    }
}

// ---------------- flash attention: split-KV (2 blocks per (b,h,qtile)) ----------------
// grid 1024 (XCD-chunked, kv-halves adjacent); 4 waves x 32 q-rows; 16 k-tiles/block;
// LDS 2x16KB double-buffer -> 4 blocks/CU, 16 waves/CU. Unnormalized O accumulated via
// global_atomic_pk_add_bf16; row-sums via f32 atomicAdd; separate normalize kernel.
__global__ __launch_bounds__(256) void flash_attn(const u16* __restrict__ Kb,
                                                  const u16* __restrict__ Kt,
                                                  u16* __restrict__ Oacc,
                                                  float* __restrict__ Ssum) {
  __shared__ char kv[2][16384];  // per buf: K [64k][128B] | V [64d][128B]
  const float S2 = 0.125f * 1.44269504088896340736f;
  int tid = threadIdx.x, lane = tid & 63, wid = tid >> 6;
  int ql = lane & 31, half = lane >> 5;
  int rb = blockIdx.x;
  int bid = (rb & 7) * 128 + (rb >> 3);  // XCD chunking: kv-pairs stay on one XCD
  int kvh = bid & 1, qt = (bid >> 1) & 15, h = (bid >> 5) & 15, b = bid >> 9;
  int qbase = b * 2048 + qt * 128 + wid * 32;
  int hc = h * 64;
  short8 qfr[4];
#pragma unroll
  for (int ds = 0; ds < 4; ++ds) {
    short8 raw = *(const short8*)(Kb + (size_t)(qbase + ql) * 1024 + hc + ds * 16 + half * 8);
    short8 q;
#pragma unroll
    for (int j = 0; j < 8; ++j) q[j] = (short)f2b(b2f((u16)raw[j]) * S2);
    qfr[ds] = q;
  }
  const short8 ones = {0x3F80, 0x3F80, 0x3F80, 0x3F80, 0x3F80, 0x3F80, 0x3F80, 0x3F80};
  f32x16 acc0 = {}, acc1 = {}, accs = {};
  int srow = lane >> 3;
  int scol = ((lane & 7) << 4) ^ (srow << 4);
  const char* Kbase = (const char*)Kb + (size_t)(b * 2048) * 2048 + hc * 2;
  const char* Vbase = (const char*)Kt + (size_t)((b * 16 + h) * 64) * 4096;

  auto stage = [&](char* buf, int kt) {
    const char* kp = Kbase + (size_t)(kt * 64) * 2048;
    const char* vp = Vbase + (size_t)(kt * 128);
    char* lk = buf;
    char* lv = buf + 8192;
#pragma unroll
    for (int j = 0; j < 2; ++j) {
      int row = wid * 8 + j * 32 + srow;
      gload16(kp + (size_t)row * 2048 + scol, lk + (wid * 8 + j * 32) * 128);
      gload16(vp + (size_t)row * 4096 + scol, lv + (wid * 8 + j * 32) * 128);
    }
  };

  int kt0 = kvh * 16;
  stage(kv[0], kt0);
  for (int i = 0; i < 16; ++i) {
    asm volatile("s_waitcnt vmcnt(0) lgkmcnt(0)" ::: "memory");
    barrier_fenced();
    if (i + 1 < 16) stage(kv[(i + 1) & 1], kt0 + i + 1);
    const char* lk = kv[i & 1];
    const char* lv = lk + 8192;
    // QK^T (swapped): A = K rows (k), B = Q^T.
    short8 kf[2][4];
#pragma unroll
    for (int kb = 0; kb < 2; ++kb)
#pragma unroll
      for (int ds = 0; ds < 4; ++ds) {
        int row = kb * 32 + ql;
        kf[kb][ds] = *(const short8*)(lk + row * 128 + ((ds * 32 + half * 16) ^ ((row & 7) << 4)));
      }
    f32x16 s0 = {}, s1 = {};
    __builtin_amdgcn_s_setprio(1);
#pragma unroll
    for (int ds = 0; ds < 4; ++ds) {
      s0 = __builtin_amdgcn_mfma_f32_32x32x16_bf16(kf[0][ds], qfr[ds], s0, 0, 0, 0);
      s1 = __builtin_amdgcn_mfma_f32_32x32x16_bf16(kf[1][ds], qfr[ds], s1, 0, 0, 0);
    }
    __builtin_amdgcn_s_setprio(0);
    // V fragments (issue early; latency hides under exp2/pack)
    short8 vf0[4], vf1[4];
#pragma unroll
    for (int ks = 0; ks < 4; ++ks) {
      int row0 = ql, row1 = 32 + ql;
      vf0[ks] = *(const short8*)(lv + row0 * 128 + ((ks * 32 + half * 16) ^ ((row0 & 7) << 4)));
      vf1[ks] = *(const short8*)(lv + row1 * 128 + ((ks * 32 + half * 16) ^ ((row1 & 7) << 4)));
    }
    // P = exp2(s); pack via v_cvt_pk_bf16_f32 (row-sum via MFMA ones-trick)
    float p[32];
#pragma unroll
    for (int j = 0; j < 16; ++j) p[j] = __builtin_amdgcn_exp2f(s0[j]);
#pragma unroll
    for (int j = 0; j < 16; ++j) p[16 + j] = __builtin_amdgcn_exp2f(s1[j]);
    u32 w0[8], w1[8];
#pragma unroll
    for (int g = 0; g < 8; ++g) {
      int idx = (g >> 2) * 16 + (g & 3) * 4;
      w0[g] = cvtpk(p[idx], p[idx + 1]);
      w1[g] = cvtpk(p[idx + 2], p[idx + 3]);
    }
    short8 pa[4];
#pragma unroll
    for (int ks = 0; ks < 4; ++ks) {
      u32 a0 = w0[2 * ks], b0 = w0[2 * ks + 1];
      u32 a1 = w1[2 * ks], b1 = w1[2 * ks + 1];
      asm volatile("v_permlane32_swap_b32 %0, %1" : "+v"(a0), "+v"(b0));
      asm volatile("v_permlane32_swap_b32 %0, %1" : "+v"(a1), "+v"(b1));
      uint4 words = {a0, a1, b0, b1};
      pa[ks] = __builtin_bit_cast(short8, words);
    }
    // PV + row-sum
    __builtin_amdgcn_s_setprio(1);
#pragma unroll
    for (int ks = 0; ks < 4; ++ks) {
      acc0 = __builtin_amdgcn_mfma_f32_32x32x16_bf16(pa[ks], vf0[ks], acc0, 0, 0, 0);
      acc1 = __builtin_amdgcn_mfma_f32_32x32x16_bf16(pa[ks], vf1[ks], acc1, 0, 0, 0);
      accs = __builtin_amdgcn_mfma_f32_32x32x16_bf16(pa[ks], ones, accs, 0, 0, 0);
    }
    __builtin_amdgcn_s_setprio(0);
  }
  // epilogue: accumulate unnormalized partials (pair adjacent cols for pk-atomic)
#pragma unroll
  for (int reg = 0; reg < 16; ++reg) {
    int ridx = (reg & 3) + 8 * (reg >> 2) + 4 * half;
    int grow = qbase + ridx;
    float o0 = acc0[reg], o1 = acc1[reg];
    float o0n = __shfl_xor(o0, 1);
    float o1n = __shfl_xor(o1, 1);
    if ((ql & 1) == 0) {
      atomPk(Oacc + (size_t)grow * 1024 + hc + ql, cvtpk(o0, o0n));
      atomPk(Oacc + (size_t)grow * 1024 + hc + 32 + ql, cvtpk(o1, o1n));
    }
    if (ql == 0) atomicAdd(&Ssum[grow * 16 + h], accs[reg]);
  }
}

// ---------------- normalize: O /= rowsum, in place (bf16) ----------------
__global__ __launch_bounds__(256) void norm_o(uint4* __restrict__ O4,
                                              const float* __restrict__ S) {
  int i = blockIdx.x * 256 + threadIdx.x;  // 524288 uint4 = 4096 x 1024 bf16
  uint4 w = O4[i];
  int row = i >> 7;            // 128 uint4 per row
  int h = (i & 127) >> 3;      // 8 uint4 per head
  float inv = __builtin_amdgcn_rcpf(S[row * 16 + h]);
  u32* wp = (u32*)&w;
#pragma unroll
  for (int j = 0; j < 4; ++j) {
    float lo = b2f((u16)(wp[j] & 0xFFFF)) * inv;
    float hi = b2f((u16)(wp[j] >> 16)) * inv;
    wp[j] = cvtpk(lo, hi);
  }
  O4[i] = w;
}

// ---------------- launch ----------------

extern "C" void kernel_launch(void* const* d_in, const int* in_sizes, int n_in, void* d_out,
                              int out_size, void* d_ws, size_t ws_size, hipStream_t stream) {
  const float* x = (const float*)d_in[0];
  const float* W_attn = (const float*)d_in[1];
  const float* b_attn = (const float*)d_in[2];
  const float* W_proj = (const float*)d_in[3];
  const float* b_proj = (const float*)d_in[4];
  float* out = (float*)d_out;
  char* ws = (char*)d_ws;
  u16* xb = (u16*)(ws);                 // 8.4MB; reused as O_accum/AO after gemm0
  u16* Kb = (u16*)(ws + 8388608);
  u16* Kt = (u16*)(ws + 16777216);
  u16* Wkt = (u16*)(ws + 25165824);     // 2MB; reused as Ssum (256KB) after gemm0
  u16* Wpt = (u16*)(ws + 27262976);

  prep<<<6144, 256, 0, stream>>>((const float4*)x, (uint2*)xb, W_attn, Wkt, W_proj, Wpt);
  gemm_bias<0><<<512, 256, 0, stream>>>(xb, Wkt, b_attn + 1024, (void*)Kb, Kt, 4096, 1024, 1024);
  // zero the accumulation buffers (xb and Wkt are dead after gemm0)
  hipMemsetAsync(xb, 0, 8388608, stream);
  hipMemsetAsync(Wkt, 0, 262144, stream);
  flash_attn<<<1024, 256, 0, stream>>>(Kb, Kt, xb, (float*)Wkt);
  norm_o<<<2048, 256, 0, stream>>>((uint4*)xb, (const float*)Wkt);
  gemm_bias<1><<<512, 256, 0, stream>>>(xb, Wpt, b_proj, (void*)out, nullptr, 4096, 1024, 1024);
}

// Round 13
// 88.562 us; speedup vs baseline: 1.3169x; 1.3169x over previous
//
#include <hip/hip_runtime.h>
#include <hip/hip_bf16.h>

typedef __attribute__((ext_vector_type(8))) short short8;
typedef __attribute__((ext_vector_type(4))) float f32x4;
typedef __attribute__((ext_vector_type(16))) float f32x16;
typedef unsigned short u16;
typedef unsigned int u32;

static __device__ __forceinline__ u16 f2b(float f) {
  __hip_bfloat16 h = __float2bfloat16(f);
  return __builtin_bit_cast(u16, h);
}
static __device__ __forceinline__ float b2f(u16 v) {
  return __builtin_bit_cast(float, ((u32)v) << 16);
}
static __device__ __forceinline__ u32 pk2(float lo, float hi) {
  return (u32)f2b(lo) | ((u32)f2b(hi) << 16);
}
static __device__ __forceinline__ u32 cvtpk(float lo, float hi) {
  u32 r;
  asm("v_cvt_pk_bf16_f32 %0, %1, %2" : "=v"(r) : "v"(lo), "v"(hi));
  return r;
}

static __device__ __forceinline__ void gload16(const void* g, void* l) {
  __builtin_amdgcn_global_load_lds((const __attribute__((address_space(1))) void*)g,
                                   (__attribute__((address_space(3))) void*)l, 16, 0, 0);
}

// Raw s_barrier has no compiler memory fence; add zero-cost scheduler+IR fences.
static __device__ __forceinline__ void barrier_fenced() {
  __builtin_amdgcn_sched_barrier(0);
  asm volatile("" ::: "memory");
  __builtin_amdgcn_s_barrier();
  __builtin_amdgcn_sched_barrier(0);
  asm volatile("" ::: "memory");
}

// ---------------- merged prep: x->bf16 | W_attn K-slice transpose | W_proj transpose ------
__global__ __launch_bounds__(256) void prep(const float4* __restrict__ x4,
                                            uint2* __restrict__ xb,
                                            const float* __restrict__ W_attn,
                                            u16* __restrict__ Wkt,
                                            const float* __restrict__ W_proj,
                                            u16* __restrict__ Wpt) {
  __shared__ u16 tile[32][33];
  int bid = blockIdx.x, t = threadIdx.x;
  if (bid < 4096) {
    int i = bid * 256 + t;
    float4 v = x4[i];
    uint2 o;
    o.x = pk2(v.x, v.y);
    o.y = pk2(v.z, v.w);
    xb[i] = o;
    return;
  }
  const float* in;
  u16* out;
  int in_rs, col_off, blk;
  if (bid < 5120) {
    in = W_attn; out = Wkt; in_rs = 3072; col_off = 1024; blk = bid - 4096;
  } else {
    in = W_proj; out = Wpt; in_rs = 1024; col_off = 0; blk = bid - 5120;
  }
  int tx = t & 31, ty = t >> 5;
  int r0 = (blk >> 5) * 32, c0 = (blk & 31) * 32;
#pragma unroll
  for (int i = 0; i < 4; ++i) {
    int r = r0 + ty + i * 8;
    tile[ty + i * 8][tx] = f2b(in[(size_t)r * in_rs + col_off + c0 + tx]);
  }
  __syncthreads();
#pragma unroll
  for (int i = 0; i < 4; ++i) {
    int c = c0 + ty + i * 8;
    out[(size_t)c * 1024 + r0 + tx] = tile[tx][ty + i * 8];
  }
}

// ---------------- GEMM: C[M][N] = A[M][K] * Bt[N][K]^T + bias ----------------
// 64x64 tile, 4 waves (2x2, 32x32 each), BK=64, double-buffered 32KB LDS, grid 1024
// (4+ blocks/CU), stage-after-barrier with vmcnt(0) drain (r10-flash proven pattern),
// XCD chunking for B-panel L2 residency. MODE 0: bf16 C + fused head transpose. MODE 1: f32.
template <int MODE>
__global__ __launch_bounds__(256) void gemm_bias(const u16* __restrict__ A,
                                                 const u16* __restrict__ Bt,
                                                 const float* __restrict__ bias,
                                                 void* __restrict__ Cp, u16* __restrict__ Ktp,
                                                 int M, int N, int K) {
  __shared__ char lds[2][16384];  // per buf: A 64x128B | B 64x128B
  int tid = threadIdx.x, lane = tid & 63, wid = tid >> 6;
  int lr = lane & 15, lh = lane >> 4;
  int rb = blockIdx.x;
  int bid = (rb & 7) * 128 + (rb >> 3);  // XCD chunking (1024 = 8 x 128)
  int m0 = (bid >> 4) << 6, n0 = (bid & 15) << 6;
  int wm = wid >> 1, wn = wid & 1;
  f32x4 acc[2][2] = {};
  int srow = lane >> 3;
  int scol = ((lane & 7) << 4) ^ (srow << 4);
  const char* Ab = (const char*)A;
  const char* Bb = (const char*)Bt;
  const int NT = K >> 6;

  auto stage = [&](char* buf, int k0) {
    char* lA = buf;
    char* lB = buf + 8192;
#pragma unroll
    for (int j = 0; j < 2; ++j) {
      int rg = wid * 16 + j * 8;  // row-group base: 0..56 step 8
      gload16(Ab + ((size_t)(m0 + rg + srow) * K + k0) * 2 + scol, lA + rg * 128);
      gload16(Bb + ((size_t)(n0 + rg + srow) * K + k0) * 2 + scol, lB + rg * 128);
    }
  };

  stage(lds[0], 0);
  for (int t = 0; t < NT; ++t) {
    asm volatile("s_waitcnt vmcnt(0) lgkmcnt(0)" ::: "memory");
    barrier_fenced();
    if (t + 1 < NT) stage(lds[(t + 1) & 1], (t + 1) << 6);
    char* lA = lds[t & 1];
    char* lB = lA + 8192;
    short8 af[2][2], bfr[2][2];
#pragma unroll
    for (int mi = 0; mi < 2; ++mi)
#pragma unroll
      for (int ks = 0; ks < 2; ++ks) {
        int row = wm * 32 + mi * 16 + lr;
        af[mi][ks] = *(const short8*)(lA + row * 128 + ((ks * 64 + lh * 16) ^ ((row & 7) << 4)));
      }
#pragma unroll
    for (int ni = 0; ni < 2; ++ni)
#pragma unroll
      for (int ks = 0; ks < 2; ++ks) {
        int row = wn * 32 + ni * 16 + lr;
        bfr[ni][ks] = *(const short8*)(lB + row * 128 + ((ks * 64 + lh * 16) ^ ((row & 7) << 4)));
      }
    __builtin_amdgcn_s_setprio(1);
#pragma unroll
    for (int ks = 0; ks < 2; ++ks)
#pragma unroll
      for (int mi = 0; mi < 2; ++mi)
#pragma unroll
        for (int ni = 0; ni < 2; ++ni)
          acc[mi][ni] = __builtin_amdgcn_mfma_f32_16x16x32_bf16(af[mi][ks], bfr[ni][ks],
                                                                acc[mi][ni], 0, 0, 0);
    __builtin_amdgcn_s_setprio(0);
  }
#pragma unroll
  for (int mi = 0; mi < 2; ++mi)
#pragma unroll
    for (int ni = 0; ni < 2; ++ni) {
      int col = n0 + wn * 32 + ni * 16 + lr;
      float bz = bias[col];
      int row0 = m0 + wm * 32 + mi * 16 + lh * 4;
      if (MODE == 1) {
#pragma unroll
        for (int r = 0; r < 4; ++r)
          ((float*)Cp)[(size_t)(row0 + r) * N + col] = acc[mi][ni][r] + bz;
      } else {
        ushort4 q;
        u16* qa = (u16*)&q;
#pragma unroll
        for (int r = 0; r < 4; ++r) {
          u16 v = f2b(acc[mi][ni][r] + bz);
          qa[r] = v;
          ((u16*)Cp)[(size_t)(row0 + r) * N + col] = v;
        }
        *(ushort4*)(Ktp + ((size_t)((row0 >> 11) * 1024 + col)) * 2048 + (row0 & 2047)) = q;
      }
    }
}

// ---------------- flash attention: pair-tile phases (r10 proven, 53.7us) ----------------
__global__ __launch_bounds__(256) void flash_attn(const u16* __restrict__ Kb,
                                                  const u16* __restrict__ Kt,
                                                  u16* __restrict__ AO) {
  __shared__ char kv[2][32768];  // per buf: 2 x (K [64k][128B] | V [64d][128B])
  const float S2 = 0.125f * 1.44269504088896340736f;
  int tid = threadIdx.x, lane = tid & 63, wid = tid >> 6;
  int ql = lane & 31, half = lane >> 5;
  int rb = blockIdx.x;
  int bid = (rb & 7) * 64 + (rb >> 3);  // XCD chunking
  int qb = bid & 15, h = (bid >> 4) & 15, b = bid >> 8;
  int qbase = b * 2048 + qb * 128 + wid * 32;
  int hc = h * 64;
  short8 qfr[4];
#pragma unroll
  for (int ds = 0; ds < 4; ++ds) {
    short8 raw = *(const short8*)(Kb + (size_t)(qbase + ql) * 1024 + hc + ds * 16 + half * 8);
    short8 q;
#pragma unroll
    for (int j = 0; j < 8; ++j) q[j] = (short)f2b(b2f((u16)raw[j]) * S2);
    qfr[ds] = q;
  }
  const short8 ones = {0x3F80, 0x3F80, 0x3F80, 0x3F80, 0x3F80, 0x3F80, 0x3F80, 0x3F80};
  f32x16 acc0 = {}, acc1 = {}, accs = {};
  int srow = lane >> 3;
  int scol = ((lane & 7) << 4) ^ (srow << 4);
  const char* Kbase = (const char*)Kb + (size_t)(b * 2048) * 2048 + hc * 2;
  const char* Vbase = (const char*)Kt + (size_t)((b * 16 + h) * 64) * 4096;

  auto stage_pair = [&](char* buf, int pt) {  // stages tiles 2pt, 2pt+1
#pragma unroll
    for (int tt = 0; tt < 2; ++tt) {
      int kt = 2 * pt + tt;
      const char* kp = Kbase + (size_t)(kt * 64) * 2048;
      const char* vp = Vbase + (size_t)(kt * 128);
      char* lk = buf + tt * 16384;
      char* lv = lk + 8192;
#pragma unroll
      for (int j = 0; j < 2; ++j) {
        int row = wid * 8 + j * 32 + srow;
        gload16(kp + (size_t)row * 2048 + scol, lk + (wid * 8 + j * 32) * 128);
        gload16(vp + (size_t)row * 4096 + scol, lv + (wid * 8 + j * 32) * 128);
      }
    }
  };

  auto read_kf = [&](const char* lk, short8 kf[2][4]) {
#pragma unroll
    for (int kb = 0; kb < 2; ++kb)
#pragma unroll
      for (int ds = 0; ds < 4; ++ds) {
        int row = kb * 32 + ql;
        kf[kb][ds] = *(const short8*)(lk + row * 128 + ((ds * 32 + half * 16) ^ ((row & 7) << 4)));
      }
  };
  auto read_vf = [&](const char* lv, short8 vf0[4], short8 vf1[4]) {
#pragma unroll
    for (int ks = 0; ks < 4; ++ks) {
      int row0 = ql, row1 = 32 + ql;
      vf0[ks] = *(const short8*)(lv + row0 * 128 + ((ks * 32 + half * 16) ^ ((row0 & 7) << 4)));
      vf1[ks] = *(const short8*)(lv + row1 * 128 + ((ks * 32 + half * 16) ^ ((row1 & 7) << 4)));
    }
  };
  auto softmax_pack = [&](const f32x16& s0, const f32x16& s1, short8 pa[4]) {
    float p[32];
#pragma unroll
    for (int i = 0; i < 16; ++i) p[i] = __builtin_amdgcn_exp2f(s0[i]);
#pragma unroll
    for (int i = 0; i < 16; ++i) p[16 + i] = __builtin_amdgcn_exp2f(s1[i]);
    u32 w0[8], w1[8];
#pragma unroll
    for (int g = 0; g < 8; ++g) {
      int idx = (g >> 2) * 16 + (g & 3) * 4;
      w0[g] = cvtpk(p[idx], p[idx + 1]);
      w1[g] = cvtpk(p[idx + 2], p[idx + 3]);
    }
#pragma unroll
    for (int ks = 0; ks < 4; ++ks) {
      u32 a0 = w0[2 * ks], b0 = w0[2 * ks + 1];
      u32 a1 = w1[2 * ks], b1 = w1[2 * ks + 1];
      asm volatile("v_permlane32_swap_b32 %0, %1" : "+v"(a0), "+v"(b0));
      asm volatile("v_permlane32_swap_b32 %0, %1" : "+v"(a1), "+v"(b1));
      uint4 words = {a0, a1, b0, b1};
      pa[ks] = __builtin_bit_cast(short8, words);
    }
  };

  stage_pair(kv[0], 0);
  for (int pt = 0; pt < 16; ++pt) {
    asm volatile("s_waitcnt vmcnt(0) lgkmcnt(0)" ::: "memory");
    barrier_fenced();
    if (pt + 1 < 16) stage_pair(kv[(pt + 1) & 1], pt + 1);
    const char* lkA = kv[pt & 1];
    const char* lvA = lkA + 8192;
    const char* lkB = lkA + 16384;
    const char* lvB = lkB + 8192;
    // ---- tile A: QK ----
    short8 kfA[2][4];
    read_kf(lkA, kfA);
    f32x16 s0 = {}, s1 = {};
    __builtin_amdgcn_s_setprio(1);
#pragma unroll
    for (int ds = 0; ds < 4; ++ds) {
      s0 = __builtin_amdgcn_mfma_f32_32x32x16_bf16(kfA[0][ds], qfr[ds], s0, 0, 0, 0);
      s1 = __builtin_amdgcn_mfma_f32_32x32x16_bf16(kfA[1][ds], qfr[ds], s1, 0, 0, 0);
    }
    __builtin_amdgcn_s_setprio(0);
    short8 vfA0[4], vfA1[4];
    read_vf(lvA, vfA0, vfA1);  // latency hides under exp2/pack A
    short8 paA[4];
    softmax_pack(s0, s1, paA);
    // ---- issue tile B K reads early: latency hides under PV-A ----
    short8 kfB[2][4];
    read_kf(lkB, kfB);
    // ---- PV-A (reg-only) ----
    __builtin_amdgcn_s_setprio(1);
#pragma unroll
    for (int ks = 0; ks < 4; ++ks) {
      acc0 = __builtin_amdgcn_mfma_f32_32x32x16_bf16(paA[ks], vfA0[ks], acc0, 0, 0, 0);
      acc1 = __builtin_amdgcn_mfma_f32_32x32x16_bf16(paA[ks], vfA1[ks], acc1, 0, 0, 0);
      accs = __builtin_amdgcn_mfma_f32_32x32x16_bf16(paA[ks], ones, accs, 0, 0, 0);
    }
    __builtin_amdgcn_s_setprio(0);
    // ---- tile B ----
    f32x16 t0 = {}, t1 = {};
    __builtin_amdgcn_s_setprio(1);
#pragma unroll
    for (int ds = 0; ds < 4; ++ds) {
      t0 = __builtin_amdgcn_mfma_f32_32x32x16_bf16(kfB[0][ds], qfr[ds], t0, 0, 0, 0);
      t1 = __builtin_amdgcn_mfma_f32_32x32x16_bf16(kfB[1][ds], qfr[ds], t1, 0, 0, 0);
    }
    __builtin_amdgcn_s_setprio(0);
    short8 vfB0[4], vfB1[4];
    read_vf(lvB, vfB0, vfB1);
    short8 paB[4];
    softmax_pack(t0, t1, paB);
    __builtin_amdgcn_s_setprio(1);
#pragma unroll
    for (int ks = 0; ks < 4; ++ks) {
      acc0 = __builtin_amdgcn_mfma_f32_32x32x16_bf16(paB[ks], vfB0[ks], acc0, 0, 0, 0);
      acc1 = __builtin_amdgcn_mfma_f32_32x32x16_bf16(paB[ks], vfB1[ks], acc1, 0, 0, 0);
      accs = __builtin_amdgcn_mfma_f32_32x32x16_bf16(paB[ks], ones, accs, 0, 0, 0);
    }
    __builtin_amdgcn_s_setprio(0);
  }
#pragma unroll
  for (int reg = 0; reg < 16; ++reg) {
    int ridx = (reg & 3) + 8 * (reg >> 2) + 4 * half;
    float iv = __builtin_amdgcn_rcpf(accs[reg]);
    int grow = qbase + ridx;
    AO[(size_t)grow * 1024 + hc + ql] = f2b(acc0[reg] * iv);
    AO[(size_t)grow * 1024 + hc + 32 + ql] = f2b(acc1[reg] * iv);
  }
}

// ---------------- launch ----------------

extern "C" void kernel_launch(void* const* d_in, const int* in_sizes, int n_in, void* d_out,
                              int out_size, void* d_ws, size_t ws_size, hipStream_t stream) {
  const float* x = (const float*)d_in[0];
  const float* W_attn = (const float*)d_in[1];
  const float* b_attn = (const float*)d_in[2];
  const float* W_proj = (const float*)d_in[3];
  const float* b_proj = (const float*)d_in[4];
  float* out = (float*)d_out;
  char* ws = (char*)d_ws;
  u16* xb = (u16*)(ws);
  u16* Kb = (u16*)(ws + 8388608);
  u16* Kt = (u16*)(ws + 16777216);
  u16* Wkt = (u16*)(ws + 25165824);
  u16* Wpt = (u16*)(ws + 27262976);

  prep<<<6144, 256, 0, stream>>>((const float4*)x, (uint2*)xb, W_attn, Wkt, W_proj, Wpt);
  gemm_bias<0><<<1024, 256, 0, stream>>>(xb, Wkt, b_attn + 1024, (void*)Kb, Kt, 4096, 1024, 1024);
  u16* AO = xb;
  flash_attn<<<512, 256, 0, stream>>>(Kb, Kt, AO);
  gemm_bias<1><<<1024, 256, 0, stream>>>(AO, Wpt, b_proj, (void*)out, nullptr, 4096, 1024, 1024);
}